// Round 12
// baseline (510.684 us; speedup 1.0000x reference)
//
#include <hip/hip_runtime.h>

// GraphAttentionLayer: B=16, M=2048, F_IN=128, F_OUT=64, ALPHA=0.2
// out = elu( softmax_j( mask(adj, leaky_relu(f1_i + f2_j)) ) @ Wh )
// Dtypes (verified R9/R11): h/W/a fp32, adj int32, out fp32.
//
// FAST path (ws >= 4.46 MB — established by R10's behavior):
//   k_pre : one wave per row, scalar Wh dot (R6-verified pattern) ->
//           WhT bf16 [b][n][j], f1, f2 (fp32) in d_ws.
//   k_attn2: 32 q-rows/block, 4 waves each own (mt half, 32-feat slice);
//           ZERO barriers in the 64-tile j-loop: A-frag (scores) in registers,
//           B-frag 16B direct loads from WhT (L2-resident), denom by-product.
// FALLBACK: R11's verified fused kernel (180 us).

#define M_     2048
#define FIN_   128
#define F_     64
#define ALPHA_ 0.2f

typedef float  float4_ __attribute__((ext_vector_type(4)));
typedef short  short4_ __attribute__((ext_vector_type(4)));
typedef short  short8  __attribute__((ext_vector_type(8)));
typedef int    int4_   __attribute__((ext_vector_type(4)));
typedef unsigned short u16;
typedef unsigned int   u32;

static __device__ __forceinline__ float bf2f(u16 u) {
    return __uint_as_float(((u32)u) << 16);
}
static __device__ __forceinline__ u16 f2bf(float f) {
    u32 u = __float_as_uint(f);
    u32 r = u + 0x7FFFu + ((u >> 16) & 1u);
    return (u16)(r >> 16);
}

// ===========================================================================
// FAST PATH
// ===========================================================================

// One wave per (b,j) row: Wh[row][n] scalar dot (R6 k1 pattern, verified);
// writes WhT[b][n][j] bf16 + f1/f2 via full-wave shuffle reduce.
// grid 8192 x 256 (4 rows per block).
__global__ __launch_bounds__(256) void k_pre(
    const float* __restrict__ h, const float* __restrict__ W,
    const float* __restrict__ a, u16* __restrict__ WhT,
    float* __restrict__ f1, float* __restrict__ f2)
{
    const int row = blockIdx.x * 4 + (threadIdx.x >> 6);   // b*M + j
    const int n   = threadIdx.x & 63;

    float acc = 0.f;
    const float* hp = h + (size_t)row * FIN_;
    for (int k = 0; k < FIN_; ++k)
        acc += hp[k] * W[k * F_ + n];

    const int b = row >> 11, jm = row & 2047;
    WhT[((size_t)b * F_ + n) * M_ + jm] = f2bf(acc);

    float s1 = acc * a[n], s2 = acc * a[F_ + n];
#pragma unroll
    for (int off = 1; off < 64; off <<= 1) {
        s1 += __shfl_xor(s1, off, 64);
        s2 += __shfl_xor(s2, off, 64);
    }
    if (n == 0) { f1[row] = s1; f2[row] = s2; }
}

// Barrier-free attention. grid 1024 x 256: b = blk>>6, i0 = (blk&63)*32.
// Wave w: mt = w&1 (16 q-rows), ntp = w>>1 (feats ntp*32 .. +32).
__global__ __launch_bounds__(256, 4) void k_attn2(
    const int* __restrict__ adj, const u16* __restrict__ WhT,
    const float* __restrict__ f1, const float* __restrict__ f2,
    float* __restrict__ out)
{
    __shared__ float f2s[M_];     // 8 KB
    __shared__ float f1s[32];
    __shared__ float dens[32];

    const int tid  = threadIdx.x;
    const int w    = tid >> 6;
    const int l    = tid & 63;
    const int lc   = l & 15;
    const int quad = l >> 4;
    const int b    = blockIdx.x >> 6;
    const int i0   = (blockIdx.x & 63) * 32;
    const int mt   = w & 1;
    const int ntp  = w >> 1;

    // stage f2[b][:] and f1 for this block's 32 rows
    {
        const float4_* src = (const float4_*)(f2 + b * M_);
        float4_* dst = (float4_*)f2s;
        for (int i = tid; i < M_ / 4; i += 256) dst[i] = src[i];
    }
    if (tid < 32) f1s[tid] = f1[b * M_ + i0 + tid];
    __syncthreads();

    const float f1r = f1s[mt * 16 + lc];
    const int*  ap  = adj + ((size_t)(b * M_ + i0 + mt * 16 + lc)) * M_ + quad * 8;
    const u16*  wp0 = WhT + (size_t)b * F_ * M_ + (size_t)(ntp * 32 + lc) * M_ + quad * 8;
    const u16*  wp1 = wp0 + (size_t)16 * M_;
    const float* fp = f2s + quad * 8;

    float4_ acc0 = (float4_){0.f, 0.f, 0.f, 0.f};
    float4_ acc1 = (float4_){0.f, 0.f, 0.f, 0.f};
    float dsum = 0.f;

    for (int it = 0; it < 64; ++it) {
        const int j0 = it * 32;
        int4_   c0 = *(const int4_*)(ap + j0);
        int4_   c1 = *(const int4_*)(ap + j0 + 4);
        float4_ g0 = *(const float4_*)(fp + j0);
        float4_ g1 = *(const float4_*)(fp + j0 + 4);

        short8 af;
        float d = 0.f;
#define GAT_SC(jj, ai, gi)                                          \
        {                                                           \
            float x_ = f1r + (gi);                                  \
            x_ = fmaxf(x_, ALPHA_ * x_);                            \
            float e_ = ((ai) > 0) ? __expf(x_) : 0.f;               \
            u16 pb_ = f2bf(e_);                                     \
            af[jj] = (short)pb_;                                    \
            d += bf2f(pb_);                                         \
        }
        GAT_SC(0, c0[0], g0[0]) GAT_SC(1, c0[1], g0[1])
        GAT_SC(2, c0[2], g0[2]) GAT_SC(3, c0[3], g0[3])
        GAT_SC(4, c1[0], g1[0]) GAT_SC(5, c1[1], g1[1])
        GAT_SC(6, c1[2], g1[2]) GAT_SC(7, c1[3], g1[3])
#undef GAT_SC
        dsum += d;

        short8 b0 = *(const short8*)(wp0 + j0);
        short8 b1 = *(const short8*)(wp1 + j0);
        acc0 = __builtin_amdgcn_mfma_f32_16x16x32_bf16(af, b0, acc0, 0, 0, 0);
        acc1 = __builtin_amdgcn_mfma_f32_16x16x32_bf16(af, b1, acc1, 0, 0, 0);
    }

    // denom for row mt*16+lc: sum the 4 quads (token slices)
    dsum += __shfl_xor(dsum, 16, 64);
    dsum += __shfl_xor(dsum, 32, 64);
    if (w < 2 && l < 16) dens[mt * 16 + l] = dsum;   // waves 2,3 are duplicates
    __syncthreads();

    // C/D: row = quad*4+mm (within mt half), col = ntp*32 + c*16 + lc
#pragma unroll
    for (int mm = 0; mm < 4; ++mm) {
        const int rr  = mt * 16 + quad * 4 + mm;
        const float den  = dens[rr];
        const float rden = (den > 0.f) ? (1.f / den) : 0.f;
        float* op = out + ((size_t)(b * M_ + i0 + rr)) * F_ + ntp * 32 + lc;
        float v0 = acc0[mm] * rden;
        float v1 = acc1[mm] * rden;
        op[0]  = v0 > 0.f ? v0 : expm1f(v0);
        op[16] = v1 > 0.f ? v1 : expm1f(v1);
    }
}

// ===========================================================================
// FALLBACK: R11's verified fused kernel (verbatim)
// ===========================================================================
#define ROWS_  32
#define TS_    36
#define WT_    132

__global__ __launch_bounds__(256, 4) void k_gat2(
    const float* __restrict__ h, const int* __restrict__ adj,
    const float* __restrict__ W, const float* __restrict__ a,
    float* __restrict__ out)
{
    __shared__ u16   Wl[FIN_ * F_];
    __shared__ float a_s[2 * F_];
    __shared__ float wa1[FIN_], wa2[FIN_];
    __shared__ float f1s[ROWS_];
    __shared__ float dens[ROWS_];
    __shared__ char  dyn[32 * WT_ * 4];

    u16*   hT   = (u16*)dyn;
    u16*   P    = (u16*)(dyn + 9216);
    float* f2t  = (float*)(dyn + 11520);
    float* Tsum = (float*)dyn;

    const int tid  = threadIdx.x;
    const int w    = tid >> 6;
    const int l    = tid & 63;
    const int lc   = l & 15;
    const int quad = l >> 4;
    const int b    = blockIdx.x >> 6;
    const int i0   = (blockIdx.x & 63) * ROWS_;

    if (tid < 128) a_s[tid] = a[tid];
    for (int e = tid; e < FIN_ * F_; e += 256) Wl[e] = f2bf(W[e]);
    __syncthreads();

    if (tid < FIN_) {
        float s1 = 0.f, s2 = 0.f;
#pragma unroll 8
        for (int n = 0; n < F_; ++n) {
            float wv = W[tid * F_ + n];
            s1 += wv * a_s[n];
            s2 += wv * a_s[F_ + n];
        }
        wa1[tid] = s1;
        wa2[tid] = s2;
    }
    __syncthreads();

    {
        const int i = tid >> 3, sub = tid & 7, k0 = sub * 16;
        const float* hp = h + ((size_t)(b * M_ + i0 + i)) * FIN_ + k0;
        float s = 0.f;
#pragma unroll
        for (int k = 0; k < 16; ++k) s += hp[k] * wa1[k0 + k];
        s += __shfl_xor(s, 1, 64);
        s += __shfl_xor(s, 2, 64);
        s += __shfl_xor(s, 4, 64);
        if (sub == 0) f1s[i] = s;
    }
    __syncthreads();

    const int prow = tid >> 3;
    const int ps   = tid & 7;
    const int sf0  = (tid & 15) * 8;
    const int stp  = (tid >> 4) * 2;
    const int mt   = w & 1;
    const int ntb  = (w >> 1) * 4;
    const float f1r = f1s[prow];
    float denacc = 0.f;

    float4_ acc[4];
#pragma unroll
    for (int c = 0; c < 4; ++c) acc[c] = (float4_){0.f, 0.f, 0.f, 0.f};

    const int*   aprow = adj + ((size_t)(b * M_ + i0 + prow)) * M_ + ps * 4;
    const float* hbase = h + ((size_t)(b * M_ + stp)) * FIN_ + sf0;

    for (int it = 0; it < 64; ++it) {
        const int j0 = it * 32;
        int4_ c4 = *(const int4_*)(aprow + j0);
        {
            const float* hp0 = hbase + (size_t)j0 * FIN_;
            const float* hp1 = hp0 + FIN_;
            float4_ x0 = *(const float4_*)hp0, x1 = *(const float4_*)(hp0 + 4);
            float4_ y0 = *(const float4_*)hp1, y1 = *(const float4_*)(hp1 + 4);
            float xa[8] = {x0[0], x0[1], x0[2], x0[3], x1[0], x1[1], x1[2], x1[3]};
            float ya[8] = {y0[0], y0[1], y0[2], y0[3], y1[0], y1[1], y1[2], y1[3]};
            float fp0 = 0.f, fp1 = 0.f;
#pragma unroll
            for (int kk = 0; kk < 8; ++kk) {
                const int k = sf0 + kk;
                u16 u0 = f2bf(xa[kk]), u1 = f2bf(ya[kk]);
                *(u32*)(hT + k * TS_ + stp) = (u32)u0 | ((u32)u1 << 16);
                fp0 += xa[kk] * wa2[k];
                fp1 += ya[kk] * wa2[k];
            }
            fp0 += __shfl_xor(fp0, 1, 64); fp1 += __shfl_xor(fp1, 1, 64);
            fp0 += __shfl_xor(fp0, 2, 64); fp1 += __shfl_xor(fp1, 2, 64);
            fp0 += __shfl_xor(fp0, 4, 64); fp1 += __shfl_xor(fp1, 4, 64);
            fp0 += __shfl_xor(fp0, 8, 64); fp1 += __shfl_xor(fp1, 8, 64);
            if ((tid & 15) == 0) { f2t[stp] = fp0; f2t[stp + 1] = fp1; }
        }
        __syncthreads();
        {
            float4_ g = *(const float4_*)(f2t + ps * 4);
            u32 pk0, pk1;
            float d = 0.f;
            {
                float x_ = f1r + g[0]; x_ = fmaxf(x_, ALPHA_ * x_);
                float e_ = (c4[0] > 0) ? __expf(x_) : 0.f;
                u16 pb = f2bf(e_); d += bf2f(pb); pk0 = (u32)pb;
            }
            {
                float x_ = f1r + g[1]; x_ = fmaxf(x_, ALPHA_ * x_);
                float e_ = (c4[1] > 0) ? __expf(x_) : 0.f;
                u16 pb = f2bf(e_); d += bf2f(pb); pk0 |= ((u32)pb << 16);
            }
            {
                float x_ = f1r + g[2]; x_ = fmaxf(x_, ALPHA_ * x_);
                float e_ = (c4[2] > 0) ? __expf(x_) : 0.f;
                u16 pb = f2bf(e_); d += bf2f(pb); pk1 = (u32)pb;
            }
            {
                float x_ = f1r + g[3]; x_ = fmaxf(x_, ALPHA_ * x_);
                float e_ = (c4[3] > 0) ? __expf(x_) : 0.f;
                u16 pb = f2bf(e_); d += bf2f(pb); pk1 |= ((u32)pb << 16);
            }
            *(u32*)(P + prow * TS_ + ps * 4)     = pk0;
            *(u32*)(P + prow * TS_ + ps * 4 + 2) = pk1;
            denacc += d;
        }
        __syncthreads();
        {
            const u16* apx = P + (mt * 16 + lc) * TS_ + quad * 8;
            short4_ a0 = *(const short4_*)apx;
            short4_ a1 = *(const short4_*)(apx + 4);
            short8 af;
            af[0] = a0[0]; af[1] = a0[1]; af[2] = a0[2]; af[3] = a0[3];
            af[4] = a1[0]; af[5] = a1[1]; af[6] = a1[2]; af[7] = a1[3];
#pragma unroll
            for (int c = 0; c < 4; ++c) {
                const u16* bp = hT + ((ntb + c) * 16 + lc) * TS_ + quad * 8;
                short4_ b0 = *(const short4_*)bp;
                short4_ b1 = *(const short4_*)(bp + 4);
                short8 bf;
                bf[0] = b0[0]; bf[1] = b0[1]; bf[2] = b0[2]; bf[3] = b0[3];
                bf[4] = b1[0]; bf[5] = b1[1]; bf[6] = b1[2]; bf[7] = b1[3];
                acc[c] = __builtin_amdgcn_mfma_f32_16x16x32_bf16(af, bf, acc[c], 0, 0, 0);
            }
        }
        __syncthreads();
    }

    denacc += __shfl_xor(denacc, 1, 64);
    denacc += __shfl_xor(denacc, 2, 64);
    denacc += __shfl_xor(denacc, 4, 64);
    if (ps == 0) dens[prow] = denacc;

#pragma unroll
    for (int c = 0; c < 4; ++c)
#pragma unroll
        for (int mm = 0; mm < 4; ++mm)
            Tsum[(mt * 16 + quad * 4 + mm) * WT_ + (ntb + c) * 16 + lc] = acc[c][mm];
    __syncthreads();

    {
        const int row = tid >> 3;
        const int n0  = (tid & 7) * 8;
        const float den  = dens[row];
        const float rden = (den > 0.f) ? (1.f / den) : 0.f;
        float u[8];
#pragma unroll
        for (int nn = 0; nn < 8; ++nn) u[nn] = 0.f;
        for (int k = 0; k < FIN_; ++k) {
            const float tv = Tsum[row * WT_ + k];
            const u16* wq = &Wl[k * F_ + n0];
#pragma unroll
            for (int nn = 0; nn < 8; ++nn) u[nn] += tv * bf2f(wq[nn]);
        }
        float4_ o0, o1;
#pragma unroll
        for (int nn = 0; nn < 8; ++nn) {
            float hv = u[nn] * rden;
            float o  = hv > 0.f ? hv : expm1f(hv);
            if (nn < 4) o0[nn] = o; else o1[nn - 4] = o;
        }
        float* op = out + ((size_t)(b * M_ + i0 + row)) * F_ + n0;
        *(float4_*)op       = o0;
        *(float4_*)(op + 4) = o1;
    }
}

// ---------------------------------------------------------------------------
extern "C" void kernel_launch(void* const* d_in, const int* in_sizes, int n_in,
                              void* d_out, int out_size, void* d_ws, size_t ws_size,
                              hipStream_t stream)
{
    (void)out_size;
    const float* h  = (const float*)d_in[0];
    const int* adjp = (const int*)d_in[1];
    const float* Wp = (const float*)d_in[2];
    const float* ap = (const float*)d_in[3];
    for (int i = 0; i < n_in; ++i) {
        long s = in_sizes[i];
        if      (s == 4194304L)  h    = (const float*)d_in[i];
        else if (s == 67108864L) adjp = (const int*)d_in[i];
        else if (s == 8192L)     Wp   = (const float*)d_in[i];
        else if (s == 128L)      ap   = (const float*)d_in[i];
    }
    float* out = (float*)d_out;

    // ws: WhT 4MB | f1 128KB | f2 128KB
    const size_t NEED = 4194304u + 131072u + 131072u;
    if (d_ws != nullptr && ws_size >= NEED) {
        char* ws = (char*)d_ws;
        u16*   WhT = (u16*)ws;
        float* f1  = (float*)(ws + 4194304);
        float* f2  = (float*)(ws + 4194304 + 131072);
        k_pre  <<<8192, 256, 0, stream>>>(h, Wp, ap, WhT, f1, f2);
        k_attn2<<<1024, 256, 0, stream>>>(adjp, WhT, f1, f2, out);
    } else {
        k_gat2<<<1024, 256, 0, stream>>>(h, adjp, Wp, ap, out);
    }
}

// Round 13
// 493.862 us; speedup vs baseline: 1.0341x; 1.0341x over previous
//
#include <hip/hip_runtime.h>

// GraphAttentionLayer: B=16, M=2048, F_IN=128, F_OUT=64, ALPHA=0.2
// out = elu( softmax_j( mask(adj, leaky_relu(f1_i + f2_j)) ) @ Wh )
// Dtypes (verified R9/R11/R12): h/W/a fp32, adj int32, out fp32.
//
// FAST path (ws >= 4.46 MB, verified working in R12):
//   k_pre  : one wave per row, scalar Wh dot -> WhT bf16 [b][n][j], f1, f2.
//   k_attn2: 32 q-rows/block, 4 waves each own (mt half, 32-feat slice);
//            barrier-free j-loop, NOW UNROLLED x4 for memory-level parallelism
//            (R12 post-mortem: 6000 cyc/iter vs 160 cyc VALU content — the
//            serial adj->score->MFMA chain had 1 load set in flight, VGPR=28).
// FALLBACK: R11's verified fused kernel.

#define M_     2048
#define FIN_   128
#define F_     64
#define ALPHA_ 0.2f

typedef float  float4_ __attribute__((ext_vector_type(4)));
typedef short  short4_ __attribute__((ext_vector_type(4)));
typedef short  short8  __attribute__((ext_vector_type(8)));
typedef int    int4_   __attribute__((ext_vector_type(4)));
typedef unsigned short u16;
typedef unsigned int   u32;

static __device__ __forceinline__ float bf2f(u16 u) {
    return __uint_as_float(((u32)u) << 16);
}
static __device__ __forceinline__ u16 f2bf(float f) {
    u32 u = __float_as_uint(f);
    u32 r = u + 0x7FFFu + ((u >> 16) & 1u);
    return (u16)(r >> 16);
}

// ===========================================================================
// FAST PATH
// ===========================================================================

// One wave per (b,j) row: scalar Wh dot; WhT[b][n][j] bf16 + f1/f2.
// grid 8192 x 256 (4 rows per block).
__global__ __launch_bounds__(256) void k_pre(
    const float* __restrict__ h, const float* __restrict__ W,
    const float* __restrict__ a, u16* __restrict__ WhT,
    float* __restrict__ f1, float* __restrict__ f2)
{
    const int row = blockIdx.x * 4 + (threadIdx.x >> 6);   // b*M + j
    const int n   = threadIdx.x & 63;

    float acc = 0.f;
    const float* hp = h + (size_t)row * FIN_;
#pragma unroll 8
    for (int k = 0; k < FIN_; ++k)
        acc += hp[k] * W[k * F_ + n];

    const int b = row >> 11, jm = row & 2047;
    WhT[((size_t)b * F_ + n) * M_ + jm] = f2bf(acc);

    float s1 = acc * a[n], s2 = acc * a[F_ + n];
#pragma unroll
    for (int off = 1; off < 64; off <<= 1) {
        s1 += __shfl_xor(s1, off, 64);
        s2 += __shfl_xor(s2, off, 64);
    }
    if (n == 0) { f1[row] = s1; f2[row] = s2; }
}

// Barrier-free attention. grid 1024 x 256: b = blk>>6, i0 = (blk&63)*32.
// Wave w: mt = w&1 (16 q-rows), ntp = w>>1 (feats ntp*32 .. +32).
__global__ __launch_bounds__(256, 4) void k_attn2(
    const int* __restrict__ adj, const u16* __restrict__ WhT,
    const float* __restrict__ f1, const float* __restrict__ f2,
    float* __restrict__ out)
{
    __shared__ float f2s[M_];     // 8 KB
    __shared__ float f1s[32];
    __shared__ float dens[32];

    const int tid  = threadIdx.x;
    const int w    = tid >> 6;
    const int l    = tid & 63;
    const int lc   = l & 15;
    const int quad = l >> 4;
    const int b    = blockIdx.x >> 6;
    const int i0   = (blockIdx.x & 63) * 32;
    const int mt   = w & 1;
    const int ntp  = w >> 1;

    // stage f2[b][:] and f1 for this block's 32 rows
    {
        const float4_* src = (const float4_*)(f2 + b * M_);
        float4_* dst = (float4_*)f2s;
        for (int i = tid; i < M_ / 4; i += 256) dst[i] = src[i];
    }
    if (tid < 32) f1s[tid] = f1[b * M_ + i0 + tid];
    __syncthreads();

    const float f1r = f1s[mt * 16 + lc];
    const int*  ap  = adj + ((size_t)(b * M_ + i0 + mt * 16 + lc)) * M_ + quad * 8;
    const u16*  wp0 = WhT + (size_t)b * F_ * M_ + (size_t)(ntp * 32 + lc) * M_ + quad * 8;
    const u16*  wp1 = wp0 + (size_t)16 * M_;
    const float* fp = f2s + quad * 8;

    float4_ acc0 = (float4_){0.f, 0.f, 0.f, 0.f};
    float4_ acc1 = (float4_){0.f, 0.f, 0.f, 0.f};
    float dsum = 0.f;

#pragma unroll 4
    for (int it = 0; it < 64; ++it) {
        const int j0 = it * 32;
        int4_   c0 = *(const int4_*)(ap + j0);
        int4_   c1 = *(const int4_*)(ap + j0 + 4);
        short8  b0 = *(const short8*)(wp0 + j0);
        short8  b1 = *(const short8*)(wp1 + j0);
        float4_ g0 = *(const float4_*)(fp + j0);
        float4_ g1 = *(const float4_*)(fp + j0 + 4);

        short8 af;
        float d = 0.f;
#define GAT_SC(jj, ai, gi)                                          \
        {                                                           \
            float x_ = f1r + (gi);                                  \
            x_ = fmaxf(x_, ALPHA_ * x_);                            \
            float e_ = ((ai) > 0) ? __expf(x_) : 0.f;               \
            u16 pb_ = f2bf(e_);                                     \
            af[jj] = (short)pb_;                                    \
            d += bf2f(pb_);                                         \
        }
        GAT_SC(0, c0[0], g0[0]) GAT_SC(1, c0[1], g0[1])
        GAT_SC(2, c0[2], g0[2]) GAT_SC(3, c0[3], g0[3])
        GAT_SC(4, c1[0], g1[0]) GAT_SC(5, c1[1], g1[1])
        GAT_SC(6, c1[2], g1[2]) GAT_SC(7, c1[3], g1[3])
#undef GAT_SC
        dsum += d;

        acc0 = __builtin_amdgcn_mfma_f32_16x16x32_bf16(af, b0, acc0, 0, 0, 0);
        acc1 = __builtin_amdgcn_mfma_f32_16x16x32_bf16(af, b1, acc1, 0, 0, 0);
    }

    // denom for row mt*16+lc: sum the 4 quads (token slices)
    dsum += __shfl_xor(dsum, 16, 64);
    dsum += __shfl_xor(dsum, 32, 64);
    if (w < 2 && l < 16) dens[mt * 16 + l] = dsum;   // waves 2,3 are duplicates
    __syncthreads();

    // C/D: row = quad*4+mm (within mt half), col = ntp*32 + c*16 + lc
#pragma unroll
    for (int mm = 0; mm < 4; ++mm) {
        const int rr  = mt * 16 + quad * 4 + mm;
        const float den  = dens[rr];
        const float rden = (den > 0.f) ? (1.f / den) : 0.f;
        float* op = out + ((size_t)(b * M_ + i0 + rr)) * F_ + ntp * 32 + lc;
        float v0 = acc0[mm] * rden;
        float v1 = acc1[mm] * rden;
        op[0]  = v0 > 0.f ? v0 : expm1f(v0);
        op[16] = v1 > 0.f ? v1 : expm1f(v1);
    }
}

// ===========================================================================
// FALLBACK: R11's verified fused kernel (verbatim)
// ===========================================================================
#define ROWS_  32
#define TS_    36
#define WT_    132

__global__ __launch_bounds__(256, 4) void k_gat2(
    const float* __restrict__ h, const int* __restrict__ adj,
    const float* __restrict__ W, const float* __restrict__ a,
    float* __restrict__ out)
{
    __shared__ u16   Wl[FIN_ * F_];
    __shared__ float a_s[2 * F_];
    __shared__ float wa1[FIN_], wa2[FIN_];
    __shared__ float f1s[ROWS_];
    __shared__ float dens[ROWS_];
    __shared__ char  dyn[32 * WT_ * 4];

    u16*   hT   = (u16*)dyn;
    u16*   P    = (u16*)(dyn + 9216);
    float* f2t  = (float*)(dyn + 11520);
    float* Tsum = (float*)dyn;

    const int tid  = threadIdx.x;
    const int w    = tid >> 6;
    const int l    = tid & 63;
    const int lc   = l & 15;
    const int quad = l >> 4;
    const int b    = blockIdx.x >> 6;
    const int i0   = (blockIdx.x & 63) * ROWS_;

    if (tid < 128) a_s[tid] = a[tid];
    for (int e = tid; e < FIN_ * F_; e += 256) Wl[e] = f2bf(W[e]);
    __syncthreads();

    if (tid < FIN_) {
        float s1 = 0.f, s2 = 0.f;
#pragma unroll 8
        for (int n = 0; n < F_; ++n) {
            float wv = W[tid * F_ + n];
            s1 += wv * a_s[n];
            s2 += wv * a_s[F_ + n];
        }
        wa1[tid] = s1;
        wa2[tid] = s2;
    }
    __syncthreads();

    {
        const int i = tid >> 3, sub = tid & 7, k0 = sub * 16;
        const float* hp = h + ((size_t)(b * M_ + i0 + i)) * FIN_ + k0;
        float s = 0.f;
#pragma unroll
        for (int k = 0; k < 16; ++k) s += hp[k] * wa1[k0 + k];
        s += __shfl_xor(s, 1, 64);
        s += __shfl_xor(s, 2, 64);
        s += __shfl_xor(s, 4, 64);
        if (sub == 0) f1s[i] = s;
    }
    __syncthreads();

    const int prow = tid >> 3;
    const int ps   = tid & 7;
    const int sf0  = (tid & 15) * 8;
    const int stp  = (tid >> 4) * 2;
    const int mt   = w & 1;
    const int ntb  = (w >> 1) * 4;
    const float f1r = f1s[prow];
    float denacc = 0.f;

    float4_ acc[4];
#pragma unroll
    for (int c = 0; c < 4; ++c) acc[c] = (float4_){0.f, 0.f, 0.f, 0.f};

    const int*   aprow = adj + ((size_t)(b * M_ + i0 + prow)) * M_ + ps * 4;
    const float* hbase = h + ((size_t)(b * M_ + stp)) * FIN_ + sf0;

    for (int it = 0; it < 64; ++it) {
        const int j0 = it * 32;
        int4_ c4 = *(const int4_*)(aprow + j0);
        {
            const float* hp0 = hbase + (size_t)j0 * FIN_;
            const float* hp1 = hp0 + FIN_;
            float4_ x0 = *(const float4_*)hp0, x1 = *(const float4_*)(hp0 + 4);
            float4_ y0 = *(const float4_*)hp1, y1 = *(const float4_*)(hp1 + 4);
            float xa[8] = {x0[0], x0[1], x0[2], x0[3], x1[0], x1[1], x1[2], x1[3]};
            float ya[8] = {y0[0], y0[1], y0[2], y0[3], y1[0], y1[1], y1[2], y1[3]};
            float fp0 = 0.f, fp1 = 0.f;
#pragma unroll
            for (int kk = 0; kk < 8; ++kk) {
                const int k = sf0 + kk;
                u16 u0 = f2bf(xa[kk]), u1 = f2bf(ya[kk]);
                *(u32*)(hT + k * TS_ + stp) = (u32)u0 | ((u32)u1 << 16);
                fp0 += xa[kk] * wa2[k];
                fp1 += ya[kk] * wa2[k];
            }
            fp0 += __shfl_xor(fp0, 1, 64); fp1 += __shfl_xor(fp1, 1, 64);
            fp0 += __shfl_xor(fp0, 2, 64); fp1 += __shfl_xor(fp1, 2, 64);
            fp0 += __shfl_xor(fp0, 4, 64); fp1 += __shfl_xor(fp1, 4, 64);
            fp0 += __shfl_xor(fp0, 8, 64); fp1 += __shfl_xor(fp1, 8, 64);
            if ((tid & 15) == 0) { f2t[stp] = fp0; f2t[stp + 1] = fp1; }
        }
        __syncthreads();
        {
            float4_ g = *(const float4_*)(f2t + ps * 4);
            u32 pk0, pk1;
            float d = 0.f;
            {
                float x_ = f1r + g[0]; x_ = fmaxf(x_, ALPHA_ * x_);
                float e_ = (c4[0] > 0) ? __expf(x_) : 0.f;
                u16 pb = f2bf(e_); d += bf2f(pb); pk0 = (u32)pb;
            }
            {
                float x_ = f1r + g[1]; x_ = fmaxf(x_, ALPHA_ * x_);
                float e_ = (c4[1] > 0) ? __expf(x_) : 0.f;
                u16 pb = f2bf(e_); d += bf2f(pb); pk0 |= ((u32)pb << 16);
            }
            {
                float x_ = f1r + g[2]; x_ = fmaxf(x_, ALPHA_ * x_);
                float e_ = (c4[2] > 0) ? __expf(x_) : 0.f;
                u16 pb = f2bf(e_); d += bf2f(pb); pk1 = (u32)pb;
            }
            {
                float x_ = f1r + g[3]; x_ = fmaxf(x_, ALPHA_ * x_);
                float e_ = (c4[3] > 0) ? __expf(x_) : 0.f;
                u16 pb = f2bf(e_); d += bf2f(pb); pk1 |= ((u32)pb << 16);
            }
            *(u32*)(P + prow * TS_ + ps * 4)     = pk0;
            *(u32*)(P + prow * TS_ + ps * 4 + 2) = pk1;
            denacc += d;
        }
        __syncthreads();
        {
            const u16* apx = P + (mt * 16 + lc) * TS_ + quad * 8;
            short4_ a0 = *(const short4_*)apx;
            short4_ a1 = *(const short4_*)(apx + 4);
            short8 af;
            af[0] = a0[0]; af[1] = a0[1]; af[2] = a0[2]; af[3] = a0[3];
            af[4] = a1[0]; af[5] = a1[1]; af[6] = a1[2]; af[7] = a1[3];
#pragma unroll
            for (int c = 0; c < 4; ++c) {
                const u16* bp = hT + ((ntb + c) * 16 + lc) * TS_ + quad * 8;
                short4_ b0 = *(const short4_*)bp;
                short4_ b1 = *(const short4_*)(bp + 4);
                short8 bf;
                bf[0] = b0[0]; bf[1] = b0[1]; bf[2] = b0[2]; bf[3] = b0[3];
                bf[4] = b1[0]; bf[5] = b1[1]; bf[6] = b1[2]; bf[7] = b1[3];
                acc[c] = __builtin_amdgcn_mfma_f32_16x16x32_bf16(af, bf, acc[c], 0, 0, 0);
            }
        }
        __syncthreads();
    }

    denacc += __shfl_xor(denacc, 1, 64);
    denacc += __shfl_xor(denacc, 2, 64);
    denacc += __shfl_xor(denacc, 4, 64);
    if (ps == 0) dens[prow] = denacc;

#pragma unroll
    for (int c = 0; c < 4; ++c)
#pragma unroll
        for (int mm = 0; mm < 4; ++mm)
            Tsum[(mt * 16 + quad * 4 + mm) * WT_ + (ntb + c) * 16 + lc] = acc[c][mm];
    __syncthreads();

    {
        const int row = tid >> 3;
        const int n0  = (tid & 7) * 8;
        const float den  = dens[row];
        const float rden = (den > 0.f) ? (1.f / den) : 0.f;
        float u[8];
#pragma unroll
        for (int nn = 0; nn < 8; ++nn) u[nn] = 0.f;
        for (int k = 0; k < FIN_; ++k) {
            const float tv = Tsum[row * WT_ + k];
            const u16* wq = &Wl[k * F_ + n0];
#pragma unroll
            for (int nn = 0; nn < 8; ++nn) u[nn] += tv * bf2f(wq[nn]);
        }
        float4_ o0, o1;
#pragma unroll
        for (int nn = 0; nn < 8; ++nn) {
            float hv = u[nn] * rden;
            float o  = hv > 0.f ? hv : expm1f(hv);
            if (nn < 4) o0[nn] = o; else o1[nn - 4] = o;
        }
        float* op = out + ((size_t)(b * M_ + i0 + row)) * F_ + n0;
        *(float4_*)op       = o0;
        *(float4_*)(op + 4) = o1;
    }
}

// ---------------------------------------------------------------------------
extern "C" void kernel_launch(void* const* d_in, const int* in_sizes, int n_in,
                              void* d_out, int out_size, void* d_ws, size_t ws_size,
                              hipStream_t stream)
{
    (void)out_size;
    const float* h  = (const float*)d_in[0];
    const int* adjp = (const int*)d_in[1];
    const float* Wp = (const float*)d_in[2];
    const float* ap = (const float*)d_in[3];
    for (int i = 0; i < n_in; ++i) {
        long s = in_sizes[i];
        if      (s == 4194304L)  h    = (const float*)d_in[i];
        else if (s == 67108864L) adjp = (const int*)d_in[i];
        else if (s == 8192L)     Wp   = (const float*)d_in[i];
        else if (s == 128L)      ap   = (const float*)d_in[i];
    }
    float* out = (float*)d_out;

    // ws: WhT 4MB | f1 128KB | f2 128KB
    const size_t NEED = 4194304u + 131072u + 131072u;
    if (d_ws != nullptr && ws_size >= NEED) {
        char* ws = (char*)d_ws;
        u16*   WhT = (u16*)ws;
        float* f1  = (float*)(ws + 4194304);
        float* f2  = (float*)(ws + 4194304 + 131072);
        k_pre  <<<8192, 256, 0, stream>>>(h, Wp, ap, WhT, f1, f2);
        k_attn2<<<1024, 256, 0, stream>>>(adjp, WhT, f1, f2, out);
    } else {
        k_gat2<<<1024, 256, 0, stream>>>(h, adjp, Wp, ap, out);
    }
}

// Round 14
// 466.039 us; speedup vs baseline: 1.0958x; 1.0597x over previous
//
#include <hip/hip_runtime.h>

// GraphAttentionLayer: B=16, M=2048, F_IN=128, F_OUT=64, ALPHA=0.2
// out = elu( softmax_j( mask(adj, leaky_relu(f1_i + f2_j)) ) @ Wh )
// Dtypes (verified R9/R11/R12/R13): h/W/a fp32, adj int32, out fp32.
//
// FAST path (ws verified working R12/R13):
//   k_pre2 : W staged in LDS fp32; 4 rows/wave (ILP-4, W reuse, 8B WhT stores);
//            per-row math bit-identical to R12's verified k_pre.
//   k_attn3: 512 thr/block, 8 waves = (mt, ntp, jh): j-range halved per wave
//            for 2x occupancy (R13 post-mortem: 16 waves/CU was the limiter);
//            partials combined via LDS. Same verified per-iter body, unroll 2.
// FALLBACK: R11's verified fused kernel.

#define M_     2048
#define FIN_   128
#define F_     64
#define ALPHA_ 0.2f

typedef float  float4_ __attribute__((ext_vector_type(4)));
typedef short  short4_ __attribute__((ext_vector_type(4)));
typedef short  short8  __attribute__((ext_vector_type(8)));
typedef int    int4_   __attribute__((ext_vector_type(4)));
typedef unsigned short u16;
typedef unsigned int   u32;

static __device__ __forceinline__ float bf2f(u16 u) {
    return __uint_as_float(((u32)u) << 16);
}
static __device__ __forceinline__ u16 f2bf(float f) {
    u32 u = __float_as_uint(f);
    u32 r = u + 0x7FFFu + ((u >> 16) & 1u);
    return (u16)(r >> 16);
}

// ===========================================================================
// FAST PATH
// ===========================================================================

// Wh precompute: grid 2048 x 256; block = 16 rows (4 rows per wave).
// Per-row accumulation order identical to R12's k_pre (bit-identical output).
__global__ __launch_bounds__(256) void k_pre2(
    const float* __restrict__ h, const float* __restrict__ W,
    const float* __restrict__ a, u16* __restrict__ WhT,
    float* __restrict__ f1, float* __restrict__ f2)
{
    __shared__ float Wl[FIN_ * F_];   // 32 KB fp32
    __shared__ float a_s[2 * F_];

    const int tid = threadIdx.x;
    const int w   = tid >> 6;
    const int n   = tid & 63;

    for (int e = tid; e < FIN_ * F_; e += 256) Wl[e] = W[e];
    if (tid < 128) a_s[tid] = a[tid];
    __syncthreads();

    const int row0 = blockIdx.x * 16 + w * 4;        // b*M + j, 4 consecutive rows
    const float* hp = h + (size_t)row0 * FIN_;

    float acc[4] = {0.f, 0.f, 0.f, 0.f};
#pragma unroll 8
    for (int k = 0; k < FIN_; ++k) {
        const float wv = Wl[k * F_ + n];
        acc[0] += hp[k] * wv;
        acc[1] += hp[FIN_ + k] * wv;
        acc[2] += hp[2 * FIN_ + k] * wv;
        acc[3] += hp[3 * FIN_ + k] * wv;
    }

    // WhT[b][n][j..j+4): 4 u16 packed into one 8B store
    const int b = row0 >> 11, jm = row0 & 2047;
    {
        short4_ pk;
#pragma unroll
        for (int r = 0; r < 4; ++r) pk[r] = (short)f2bf(acc[r]);
        *(short4_*)(WhT + ((size_t)b * F_ + n) * M_ + jm) = pk;
    }

    // f1/f2 per row: full-wave shuffle reduce (same tree as verified k_pre)
#pragma unroll
    for (int r = 0; r < 4; ++r) {
        float s1 = acc[r] * a_s[n], s2 = acc[r] * a_s[F_ + n];
#pragma unroll
        for (int off = 1; off < 64; off <<= 1) {
            s1 += __shfl_xor(s1, off, 64);
            s2 += __shfl_xor(s2, off, 64);
        }
        if (n == 0) { f1[row0 + r] = s1; f2[row0 + r] = s2; }
    }
}

// Attention: grid 1024 x 512. b = blk>>6, i0 = (blk&63)*32.
// Wave w: mt = w&1 (q-row half), ntp = (w>>1)&1 (feat half), jh = w>>2 (j half).
__global__ __launch_bounds__(512, 8) void k_attn3(
    const int* __restrict__ adj, const u16* __restrict__ WhT,
    const float* __restrict__ f1, const float* __restrict__ f2,
    float* __restrict__ out)
{
    __shared__ float f2s[M_];            // 8 KB
    __shared__ float f1s[32];
    __shared__ float accT[2][32][66];    // 16.5 KB  partial T per j-half
    __shared__ float dens2[2][32];       // 256 B

    const int tid  = threadIdx.x;
    const int w    = tid >> 6;
    const int l    = tid & 63;
    const int lc   = l & 15;
    const int quad = l >> 4;
    const int b    = blockIdx.x >> 6;
    const int i0   = (blockIdx.x & 63) * 32;
    const int mt   = w & 1;
    const int ntp  = (w >> 1) & 1;
    const int jh   = w >> 2;

    {
        const float4_* src = (const float4_*)(f2 + b * M_);
        float4_* dst = (float4_*)f2s;
        for (int i = tid; i < M_ / 4; i += 512) dst[i] = src[i];
    }
    if (tid < 32) f1s[tid] = f1[b * M_ + i0 + tid];
    __syncthreads();

    const float f1r = f1s[mt * 16 + lc];
    const int*  ap  = adj + ((size_t)(b * M_ + i0 + mt * 16 + lc)) * M_ + quad * 8;
    const u16*  wp0 = WhT + (size_t)b * F_ * M_ + (size_t)(ntp * 32 + lc) * M_ + quad * 8;
    const u16*  wp1 = wp0 + (size_t)16 * M_;
    const float* fp = f2s + quad * 8;

    float4_ acc0 = (float4_){0.f, 0.f, 0.f, 0.f};
    float4_ acc1 = (float4_){0.f, 0.f, 0.f, 0.f};
    float dsum = 0.f;

    const int itEnd = jh * 32 + 32;
#pragma unroll 2
    for (int it = jh * 32; it < itEnd; ++it) {
        const int j0 = it * 32;
        int4_   c0 = *(const int4_*)(ap + j0);
        int4_   c1 = *(const int4_*)(ap + j0 + 4);
        short8  b0 = *(const short8*)(wp0 + j0);
        short8  b1 = *(const short8*)(wp1 + j0);
        float4_ g0 = *(const float4_*)(fp + j0);
        float4_ g1 = *(const float4_*)(fp + j0 + 4);

        short8 af;
        float d = 0.f;
#define GAT_SC(jj, ai, gi)                                          \
        {                                                           \
            float x_ = f1r + (gi);                                  \
            x_ = fmaxf(x_, ALPHA_ * x_);                            \
            float e_ = ((ai) > 0) ? __expf(x_) : 0.f;               \
            u16 pb_ = f2bf(e_);                                     \
            af[jj] = (short)pb_;                                    \
            d += bf2f(pb_);                                         \
        }
        GAT_SC(0, c0[0], g0[0]) GAT_SC(1, c0[1], g0[1])
        GAT_SC(2, c0[2], g0[2]) GAT_SC(3, c0[3], g0[3])
        GAT_SC(4, c1[0], g1[0]) GAT_SC(5, c1[1], g1[1])
        GAT_SC(6, c1[2], g1[2]) GAT_SC(7, c1[3], g1[3])
#undef GAT_SC
        dsum += d;

        acc0 = __builtin_amdgcn_mfma_f32_16x16x32_bf16(af, b0, acc0, 0, 0, 0);
        acc1 = __builtin_amdgcn_mfma_f32_16x16x32_bf16(af, b1, acc1, 0, 0, 0);
    }

    // partial denom for row mt*16+lc over this j-half (ntp==0 waves only)
    dsum += __shfl_xor(dsum, 16, 64);
    dsum += __shfl_xor(dsum, 32, 64);
    if (ntp == 0 && l < 16) dens2[jh][mt * 16 + l] = dsum;

    // partial T -> LDS. C/D: row = quad*4+mm, col = ntp*32 + lc (+16)
#pragma unroll
    for (int mm = 0; mm < 4; ++mm) {
        const int rr = mt * 16 + quad * 4 + mm;
        accT[jh][rr][ntp * 32 + lc]      = acc0[mm];
        accT[jh][rr][ntp * 32 + 16 + lc] = acc1[mm];
    }
    __syncthreads();

    // combine halves + normalize + ELU + store (512 thr: 4 outputs each)
    {
        const int row = tid >> 4;
        const int n0  = (tid & 15) * 4;
        const float den  = dens2[0][row] + dens2[1][row];
        const float rden = (den > 0.f) ? (1.f / den) : 0.f;
        float4_ o;
#pragma unroll
        for (int c = 0; c < 4; ++c) {
            float v = (accT[0][row][n0 + c] + accT[1][row][n0 + c]) * rden;
            o[c] = v > 0.f ? v : expm1f(v);
        }
        *(float4_*)(out + ((size_t)(b * M_ + i0 + row)) * F_ + n0) = o;
    }
}

// ===========================================================================
// FALLBACK: R11's verified fused kernel (verbatim)
// ===========================================================================
#define ROWS_  32
#define TS_    36
#define WT_    132

__global__ __launch_bounds__(256, 4) void k_gat2(
    const float* __restrict__ h, const int* __restrict__ adj,
    const float* __restrict__ W, const float* __restrict__ a,
    float* __restrict__ out)
{
    __shared__ u16   Wl[FIN_ * F_];
    __shared__ float a_s[2 * F_];
    __shared__ float wa1[FIN_], wa2[FIN_];
    __shared__ float f1s[ROWS_];
    __shared__ float dens[ROWS_];
    __shared__ char  dyn[32 * WT_ * 4];

    u16*   hT   = (u16*)dyn;
    u16*   P    = (u16*)(dyn + 9216);
    float* f2t  = (float*)(dyn + 11520);
    float* Tsum = (float*)dyn;

    const int tid  = threadIdx.x;
    const int w    = tid >> 6;
    const int l    = tid & 63;
    const int lc   = l & 15;
    const int quad = l >> 4;
    const int b    = blockIdx.x >> 6;
    const int i0   = (blockIdx.x & 63) * ROWS_;

    if (tid < 128) a_s[tid] = a[tid];
    for (int e = tid; e < FIN_ * F_; e += 256) Wl[e] = f2bf(W[e]);
    __syncthreads();

    if (tid < FIN_) {
        float s1 = 0.f, s2 = 0.f;
#pragma unroll 8
        for (int n = 0; n < F_; ++n) {
            float wv = W[tid * F_ + n];
            s1 += wv * a_s[n];
            s2 += wv * a_s[F_ + n];
        }
        wa1[tid] = s1;
        wa2[tid] = s2;
    }
    __syncthreads();

    {
        const int i = tid >> 3, sub = tid & 7, k0 = sub * 16;
        const float* hp = h + ((size_t)(b * M_ + i0 + i)) * FIN_ + k0;
        float s = 0.f;
#pragma unroll
        for (int k = 0; k < 16; ++k) s += hp[k] * wa1[k0 + k];
        s += __shfl_xor(s, 1, 64);
        s += __shfl_xor(s, 2, 64);
        s += __shfl_xor(s, 4, 64);
        if (sub == 0) f1s[i] = s;
    }
    __syncthreads();

    const int prow = tid >> 3;
    const int ps   = tid & 7;
    const int sf0  = (tid & 15) * 8;
    const int stp  = (tid >> 4) * 2;
    const int mt   = w & 1;
    const int ntb  = (w >> 1) * 4;
    const float f1r = f1s[prow];
    float denacc = 0.f;

    float4_ acc[4];
#pragma unroll
    for (int c = 0; c < 4; ++c) acc[c] = (float4_){0.f, 0.f, 0.f, 0.f};

    const int*   aprow = adj + ((size_t)(b * M_ + i0 + prow)) * M_ + ps * 4;
    const float* hbase = h + ((size_t)(b * M_ + stp)) * FIN_ + sf0;

    for (int it = 0; it < 64; ++it) {
        const int j0 = it * 32;
        int4_ c4 = *(const int4_*)(aprow + j0);
        {
            const float* hp0 = hbase + (size_t)j0 * FIN_;
            const float* hp1 = hp0 + FIN_;
            float4_ x0 = *(const float4_*)hp0, x1 = *(const float4_*)(hp0 + 4);
            float4_ y0 = *(const float4_*)hp1, y1 = *(const float4_*)(hp1 + 4);
            float xa[8] = {x0[0], x0[1], x0[2], x0[3], x1[0], x1[1], x1[2], x1[3]};
            float ya[8] = {y0[0], y0[1], y0[2], y0[3], y1[0], y1[1], y1[2], y1[3]};
            float fp0 = 0.f, fp1 = 0.f;
#pragma unroll
            for (int kk = 0; kk < 8; ++kk) {
                const int k = sf0 + kk;
                u16 u0 = f2bf(xa[kk]), u1 = f2bf(ya[kk]);
                *(u32*)(hT + k * TS_ + stp) = (u32)u0 | ((u32)u1 << 16);
                fp0 += xa[kk] * wa2[k];
                fp1 += ya[kk] * wa2[k];
            }
            fp0 += __shfl_xor(fp0, 1, 64); fp1 += __shfl_xor(fp1, 1, 64);
            fp0 += __shfl_xor(fp0, 2, 64); fp1 += __shfl_xor(fp1, 2, 64);
            fp0 += __shfl_xor(fp0, 4, 64); fp1 += __shfl_xor(fp1, 4, 64);
            fp0 += __shfl_xor(fp0, 8, 64); fp1 += __shfl_xor(fp1, 8, 64);
            if ((tid & 15) == 0) { f2t[stp] = fp0; f2t[stp + 1] = fp1; }
        }
        __syncthreads();
        {
            float4_ g = *(const float4_*)(f2t + ps * 4);
            u32 pk0, pk1;
            float d = 0.f;
            {
                float x_ = f1r + g[0]; x_ = fmaxf(x_, ALPHA_ * x_);
                float e_ = (c4[0] > 0) ? __expf(x_) : 0.f;
                u16 pb = f2bf(e_); d += bf2f(pb); pk0 = (u32)pb;
            }
            {
                float x_ = f1r + g[1]; x_ = fmaxf(x_, ALPHA_ * x_);
                float e_ = (c4[1] > 0) ? __expf(x_) : 0.f;
                u16 pb = f2bf(e_); d += bf2f(pb); pk0 |= ((u32)pb << 16);
            }
            {
                float x_ = f1r + g[2]; x_ = fmaxf(x_, ALPHA_ * x_);
                float e_ = (c4[2] > 0) ? __expf(x_) : 0.f;
                u16 pb = f2bf(e_); d += bf2f(pb); pk1 = (u32)pb;
            }
            {
                float x_ = f1r + g[3]; x_ = fmaxf(x_, ALPHA_ * x_);
                float e_ = (c4[3] > 0) ? __expf(x_) : 0.f;
                u16 pb = f2bf(e_); d += bf2f(pb); pk1 |= ((u32)pb << 16);
            }
            *(u32*)(P + prow * TS_ + ps * 4)     = pk0;
            *(u32*)(P + prow * TS_ + ps * 4 + 2) = pk1;
            denacc += d;
        }
        __syncthreads();
        {
            const u16* apx = P + (mt * 16 + lc) * TS_ + quad * 8;
            short4_ a0 = *(const short4_*)apx;
            short4_ a1 = *(const short4_*)(apx + 4);
            short8 af;
            af[0] = a0[0]; af[1] = a0[1]; af[2] = a0[2]; af[3] = a0[3];
            af[4] = a1[0]; af[5] = a1[1]; af[6] = a1[2]; af[7] = a1[3];
#pragma unroll
            for (int c = 0; c < 4; ++c) {
                const u16* bp = hT + ((ntb + c) * 16 + lc) * TS_ + quad * 8;
                short4_ b0 = *(const short4_*)bp;
                short4_ b1 = *(const short4_*)(bp + 4);
                short8 bf;
                bf[0] = b0[0]; bf[1] = b0[1]; bf[2] = b0[2]; bf[3] = b0[3];
                bf[4] = b1[0]; bf[5] = b1[1]; bf[6] = b1[2]; bf[7] = b1[3];
                acc[c] = __builtin_amdgcn_mfma_f32_16x16x32_bf16(af, bf, acc[c], 0, 0, 0);
            }
        }
        __syncthreads();
    }

    denacc += __shfl_xor(denacc, 1, 64);
    denacc += __shfl_xor(denacc, 2, 64);
    denacc += __shfl_xor(denacc, 4, 64);
    if (ps == 0) dens[prow] = denacc;

#pragma unroll
    for (int c = 0; c < 4; ++c)
#pragma unroll
        for (int mm = 0; mm < 4; ++mm)
            Tsum[(mt * 16 + quad * 4 + mm) * WT_ + (ntb + c) * 16 + lc] = acc[c][mm];
    __syncthreads();

    {
        const int row = tid >> 3;
        const int n0  = (tid & 7) * 8;
        const float den  = dens[row];
        const float rden = (den > 0.f) ? (1.f / den) : 0.f;
        float u[8];
#pragma unroll
        for (int nn = 0; nn < 8; ++nn) u[nn] = 0.f;
        for (int k = 0; k < FIN_; ++k) {
            const float tv = Tsum[row * WT_ + k];
            const u16* wq = &Wl[k * F_ + n0];
#pragma unroll
            for (int nn = 0; nn < 8; ++nn) u[nn] += tv * bf2f(wq[nn]);
        }
        float4_ o0, o1;
#pragma unroll
        for (int nn = 0; nn < 8; ++nn) {
            float hv = u[nn] * rden;
            float o  = hv > 0.f ? hv : expm1f(hv);
            if (nn < 4) o0[nn] = o; else o1[nn - 4] = o;
        }
        float* op = out + ((size_t)(b * M_ + i0 + row)) * F_ + n0;
        *(float4_*)op       = o0;
        *(float4_*)(op + 4) = o1;
    }
}

// ---------------------------------------------------------------------------
extern "C" void kernel_launch(void* const* d_in, const int* in_sizes, int n_in,
                              void* d_out, int out_size, void* d_ws, size_t ws_size,
                              hipStream_t stream)
{
    (void)out_size;
    const float* h  = (const float*)d_in[0];
    const int* adjp = (const int*)d_in[1];
    const float* Wp = (const float*)d_in[2];
    const float* ap = (const float*)d_in[3];
    for (int i = 0; i < n_in; ++i) {
        long s = in_sizes[i];
        if      (s == 4194304L)  h    = (const float*)d_in[i];
        else if (s == 67108864L) adjp = (const int*)d_in[i];
        else if (s == 8192L)     Wp   = (const float*)d_in[i];
        else if (s == 128L)      ap   = (const float*)d_in[i];
    }
    float* out = (float*)d_out;

    // ws: WhT 4MB | f1 128KB | f2 128KB
    const size_t NEED = 4194304u + 131072u + 131072u;
    if (d_ws != nullptr && ws_size >= NEED) {
        char* ws = (char*)d_ws;
        u16*   WhT = (u16*)ws;
        float* f1  = (float*)(ws + 4194304);
        float* f2  = (float*)(ws + 4194304 + 131072);
        k_pre2 <<<2048, 256, 0, stream>>>(h, Wp, ap, WhT, f1, f2);
        k_attn3<<<1024, 512, 0, stream>>>(adjp, WhT, f1, f2, out);
    } else {
        k_gat2<<<1024, 256, 0, stream>>>(h, adjp, Wp, ap, out);
    }
}